// Round 1
// baseline (61.774 us; speedup 1.0000x reference)
//
#include <hip/hip_runtime.h>

// Problem constants (fixed by the reference's setup_inputs).
#define LSEQ 512      // sequence length
#define NMUT 65536    // number of mutations
#define DDIM 128      // hidden dim
#define VOCAB 21
#define KCONV 9
#define TAB_STRIDE 32 // padded row stride for tab[pos][vocab]

// ---------------------------------------------------------------------------
// Kernel 1: for each position p in [0, LSEQ), run the (collapsed) model:
//   x = all_input[p]                         [128]
//   feat = x @ Wf[:,:,4].T + bf              (conv1d k=9 on len-1 seq = center tap)
//   (attention softmax over len-1 axis == 1 -> h = feat; Wa/ba unused)
//   h = relu(h) @ W1.T + b1 ; relu @ W2.T + b2 ; relu @ W3.T + b3 ; relu @ W4.T + b4
//   tab[p][v] = logits[v] * Wd + bd
// One block per position, 128 threads (one per output feature).
// ---------------------------------------------------------------------------
__global__ __launch_bounds__(128) void precompute_tab_kernel(
    const float* __restrict__ all_input,
    const float* __restrict__ Wf, const float* __restrict__ bf,
    const float* __restrict__ W1, const float* __restrict__ b1,
    const float* __restrict__ W2, const float* __restrict__ b2,
    const float* __restrict__ W3, const float* __restrict__ b3,
    const float* __restrict__ W4, const float* __restrict__ b4,
    const float* __restrict__ Wd, const float* __restrict__ bd,
    float* __restrict__ tab)
{
    __shared__ float xs[DDIM];
    __shared__ float ha[DDIM];
    __shared__ float hb[DDIM];

    const int p = blockIdx.x;
    const int o = threadIdx.x;

    xs[o] = all_input[p * DDIM + o];
    __syncthreads();

    // feat = x @ WfC^T + bf  (center tap: Wf[o][i][4] at flat (o*128+i)*9+4)
    float acc = bf[o];
    #pragma unroll 4
    for (int i = 0; i < DDIM; ++i)
        acc = fmaf(xs[i], Wf[(o * DDIM + i) * KCONV + 4], acc);
    ha[o] = fmaxf(acc, 0.0f);           // store relu(feat): only consumed post-relu
    __syncthreads();

    // W1: 128 -> 128
    acc = b1[o];
    #pragma unroll 4
    for (int i = 0; i < DDIM; ++i)
        acc = fmaf(ha[i], W1[o * DDIM + i], acc);
    hb[o] = fmaxf(acc, 0.0f);
    __syncthreads();

    // W2: 128 -> 64
    if (o < 64) {
        acc = b2[o];
        #pragma unroll 4
        for (int i = 0; i < 128; ++i)
            acc = fmaf(hb[i], W2[o * 128 + i], acc);
        ha[o] = fmaxf(acc, 0.0f);
    }
    __syncthreads();

    // W3: 64 -> 32
    if (o < 32) {
        acc = b3[o];
        #pragma unroll 4
        for (int i = 0; i < 64; ++i)
            acc = fmaf(ha[i], W3[o * 64 + i], acc);
        hb[o] = fmaxf(acc, 0.0f);
    }
    __syncthreads();

    // W4: 32 -> 21, then ddg_out = logits*Wd + bd
    if (o < VOCAB) {
        acc = b4[o];
        #pragma unroll
        for (int i = 0; i < 32; ++i)
            acc = fmaf(hb[i], W4[o * 32 + i], acc);
        tab[p * TAB_STRIDE + o] = acc * Wd[0] + bd[0];
    }
}

// ---------------------------------------------------------------------------
// Kernel 2: one wave (64 lanes) per mutation row.
// Scan the row vs wildtype in 8 coalesced chunks of 64 ints; early-exit on
// the first chunk containing a mismatch (ballot is wave-uniform).
//   pred = tab[pos][wt[pos]] - tab[pos][mut[pos]]; real = nrgs[row]
// ---------------------------------------------------------------------------
__global__ __launch_bounds__(256) void ddg_scan_kernel(
    const int*   __restrict__ wt,     // [LSEQ]
    const int*   __restrict__ muts,   // [NMUT, LSEQ]
    const float* __restrict__ nrgs,   // [NMUT]
    const float* __restrict__ tab,    // [LSEQ, TAB_STRIDE]
    float* __restrict__ preds,        // [NMUT]
    float* __restrict__ reals)        // [NMUT]
{
    __shared__ int wts[LSEQ];
    const int tid = threadIdx.x;
    wts[tid]       = wt[tid];
    wts[tid + 256] = wt[tid + 256];
    __syncthreads();

    const int wave = tid >> 6;
    const int lane = tid & 63;
    const int row  = blockIdx.x * 4 + wave;
    const int* __restrict__ mrow = muts + (size_t)row * LSEQ;

    bool found = false;
    int pos = 0, mc = 0, wc = 0;

    for (int c = 0; c < LSEQ / 64; ++c) {
        const int m = mrow[c * 64 + lane];
        const int w = wts[c * 64 + lane];
        const unsigned long long msk = __ballot(m != w);   // wave-uniform
        if (msk) {
            const int fl = __ffsll(msk) - 1;               // first mismatching lane
            pos = c * 64 + fl;
            mc  = __shfl(m, fl);
            wc  = __shfl(w, fl);
            found = true;
            break;
        }
    }

    float pred = 0.0f, real = 0.0f;
    if (found) {
        pred = tab[pos * TAB_STRIDE + wc] - tab[pos * TAB_STRIDE + mc];
        real = nrgs[row];
    }
    if (lane == 0) {
        preds[row] = pred;
        reals[row] = real;
    }
}

extern "C" void kernel_launch(void* const* d_in, const int* in_sizes, int n_in,
                              void* d_out, int out_size, void* d_ws, size_t ws_size,
                              hipStream_t stream) {
    const float* all_input = (const float*)d_in[0];   // [512,128]
    const int*   seqs      = (const int*)  d_in[1];   // [1,512]
    const int*   muts      = (const int*)  d_in[2];   // [1,65536,512]
    const float* nrgs      = (const float*)d_in[3];   // [1,65536]
    const float* Wf        = (const float*)d_in[4];   // [128,128,9]
    const float* bf        = (const float*)d_in[5];
    // d_in[6] = Wa, d_in[7] = ba : dead (softmax over length-1 axis == 1)
    const float* W1 = (const float*)d_in[8];
    const float* b1 = (const float*)d_in[9];
    const float* W2 = (const float*)d_in[10];
    const float* b2 = (const float*)d_in[11];
    const float* W3 = (const float*)d_in[12];
    const float* b3 = (const float*)d_in[13];
    const float* W4 = (const float*)d_in[14];
    const float* b4 = (const float*)d_in[15];
    const float* Wd = (const float*)d_in[16];
    const float* bd = (const float*)d_in[17];

    float* tab   = (float*)d_ws;            // 512*32*4 = 64 KiB
    float* preds = (float*)d_out;           // [NMUT]
    float* reals = (float*)d_out + NMUT;    // [NMUT]

    precompute_tab_kernel<<<LSEQ, 128, 0, stream>>>(
        all_input, Wf, bf, W1, b1, W2, b2, W3, b3, W4, b4, Wd, bd, tab);

    ddg_scan_kernel<<<NMUT / 4, 256, 0, stream>>>(
        seqs, muts, nrgs, tab, preds, reals);
}

// Round 2
// 46.217 us; speedup vs baseline: 1.3366x; 1.3366x over previous
//
#include <hip/hip_runtime.h>

// Problem constants (fixed by the reference's setup_inputs).
#define LSEQ 512      // sequence length
#define NMUT 65536    // number of mutations
#define DDIM 128      // hidden dim
#define VOCAB 21
#define KCONV 9
#define TABS 32       // padded tab row stride
#define PPB 8         // positions per tab block
#define NB_TAB (LSEQ / PPB)                 // 64 tab blocks
#define ROWS_PER_WAVE 8
#define NB_SCAN (NMUT / (4 * ROWS_PER_WAVE)) // 2048 scan blocks

// Dense layer: dst[o][p] = relu?(b[o] + sum_i src[i][p] * W[(o*IN+i)*WSTRIDE + WOFF])
// 256 threads: t<128 -> o=t, positions 0..3; t>=128 -> o=t-128, positions 4..7.
// src reads are wave-uniform LDS broadcasts (conflict-free float4).
template<int IN, int OUT, int WSTRIDE, int WOFF, bool RELU>
__device__ __forceinline__ void layer_f(const float* __restrict__ W,
                                        const float* __restrict__ b,
                                        const float (* __restrict__ src)[PPB],
                                        float (* __restrict__ dst)[PPB],
                                        int t)
{
    const int ph = t >> 7;
    const int o  = t & 127;
    if (o < OUT) {
        const float bias = b[o];
        float4 acc = make_float4(bias, bias, bias, bias);
        const float* Wr = W + (size_t)o * IN * WSTRIDE + WOFF;
        #pragma unroll 4
        for (int i = 0; i < IN; ++i) {
            const float w = Wr[(size_t)i * WSTRIDE];
            const float4 x = *(const float4*)&src[i][ph * 4];
            acc.x = fmaf(x.x, w, acc.x);
            acc.y = fmaf(x.y, w, acc.y);
            acc.z = fmaf(x.z, w, acc.z);
            acc.w = fmaf(x.w, w, acc.w);
        }
        if (RELU) {
            acc.x = fmaxf(acc.x, 0.f); acc.y = fmaxf(acc.y, 0.f);
            acc.z = fmaxf(acc.z, 0.f); acc.w = fmaxf(acc.w, 0.f);
        }
        *(float4*)&dst[o][ph * 4] = acc;
    }
}

// Probe one 128-int chunk (int2 per lane). pos/wc/mc updated wave-uniformly.
#define SCAN_CHUNK(C, WREG)                                                   \
    if (pos < 0) {                                                            \
        const int2 a = mrow[(C) * 64 + lane];                                 \
        const int bb0 = (a.x != (WREG).x ? 1 : 0) | (a.y != (WREG).y ? 2 : 0);\
        const unsigned long long msk = __ballot(bb0 != 0);                    \
        if (msk) {                                                            \
            const int fl = __ffsll((unsigned long long)msk) - 1;              \
            const int bb = __shfl(bb0, fl);                                   \
            const int j  = (bb & 1) ? 0 : 1;                                  \
            pos = (C) * 128 + fl * 2 + j;                                     \
            mc  = __shfl(j ? a.y : a.x, fl);                                  \
            wc  = __shfl(j ? (WREG).y : (WREG).x, fl);                        \
        }                                                                     \
    }

// Fused kernel: blocks [0, NB_TAB) compute the 512x21 ddg table (MLP collapsed:
// softmax over len-1 axis == 1, so Wa/ba dead and h = feat). Blocks
// [NB_TAB, NB_TAB+NB_SCAN) scan mutation rows for the first mismatch and emit
// packed meta = pos | wc<<16 | mc<<24. The two are independent; scan dominates.
__global__ __launch_bounds__(256, 6) void fused_tab_scan_kernel(
    const float* __restrict__ all_input,
    const int*   __restrict__ wt,
    const int*   __restrict__ muts,
    const float* __restrict__ Wf, const float* __restrict__ bf,
    const float* __restrict__ W1, const float* __restrict__ b1,
    const float* __restrict__ W2, const float* __restrict__ b2,
    const float* __restrict__ W3, const float* __restrict__ b3,
    const float* __restrict__ W4, const float* __restrict__ b4,
    const float* __restrict__ Wd, const float* __restrict__ bd,
    float* __restrict__ tab, int* __restrict__ meta)
{
    __shared__ float bufA[DDIM][PPB];   // activations, transposed [i][p]
    __shared__ float bufB[DDIM][PPB];
    const int tid = threadIdx.x;

    if (blockIdx.x < NB_TAB) {
        // ---------------- tab path: 8 positions through the collapsed MLP ---
        const int p0 = blockIdx.x * PPB;
        #pragma unroll
        for (int k = 0; k < 4; ++k) {
            const int f = tid + k * 256;            // f = p*128 + i, coalesced
            bufA[f & 127][f >> 7] = all_input[p0 * DDIM + f];
        }
        __syncthreads();
        layer_f<128, 128, KCONV, KCONV / 2, true>(Wf, bf, bufA, bufB, tid); // conv center tap
        __syncthreads();
        layer_f<128, 128, 1, 0, true>(W1, b1, bufB, bufA, tid);
        __syncthreads();
        layer_f<128, 64, 1, 0, true>(W2, b2, bufA, bufB, tid);
        __syncthreads();
        layer_f<64, 32, 1, 0, true>(W3, b3, bufB, bufA, tid);
        __syncthreads();
        // Final layer 32 -> 21 (no relu), fold in ddg_out Linear(1,1).
        const int ph = tid >> 7;
        const int o  = tid & 127;
        if (o < VOCAB) {
            const float wd = Wd[0], bdv = bd[0];
            const float bias = b4[o];
            float4 acc = make_float4(bias, bias, bias, bias);
            #pragma unroll
            for (int i = 0; i < 32; ++i) {
                const float w = W4[o * 32 + i];
                const float4 x = *(const float4*)&bufA[i][ph * 4];
                acc.x = fmaf(x.x, w, acc.x);
                acc.y = fmaf(x.y, w, acc.y);
                acc.z = fmaf(x.z, w, acc.z);
                acc.w = fmaf(x.w, w, acc.w);
            }
            const int pb = p0 + ph * 4;
            tab[(pb + 0) * TABS + o] = acc.x * wd + bdv;
            tab[(pb + 1) * TABS + o] = acc.y * wd + bdv;
            tab[(pb + 2) * TABS + o] = acc.z * wd + bdv;
            tab[(pb + 3) * TABS + o] = acc.w * wd + bdv;
        }
        return;
    }

    // ---------------- scan path: one wave per row, 128-int chunks ----------
    const int lane = tid & 63;
    const int wgid = (blockIdx.x - NB_TAB) * 4 + (tid >> 6);
    const int2* __restrict__ wt2 = (const int2*)wt;
    const int2 w0 = wt2[lane];
    const int2 w1r = wt2[64 + lane];
    const int2 w2r = wt2[128 + lane];
    const int2 w3r = wt2[192 + lane];

    const int rbase = wgid * ROWS_PER_WAVE;
    for (int k = 0; k < ROWS_PER_WAVE; ++k) {
        const int row = rbase + k;
        const int2* __restrict__ mrow = (const int2*)(muts + (size_t)row * LSEQ);
        int pos = -1, wc = 0, mc = 0;
        SCAN_CHUNK(0, w0);
        SCAN_CHUNK(1, w1r);
        SCAN_CHUNK(2, w2r);
        SCAN_CHUNK(3, w3r);
        if (lane == 0)
            meta[row] = (pos < 0) ? -1 : (pos | (wc << 16) | (mc << 24));
    }
}

// Apply table lookup: pred = tab[pos][wc] - tab[pos][mc]; real = nrgs[row].
__global__ __launch_bounds__(256) void lookup_kernel(
    const int*   __restrict__ meta,
    const float* __restrict__ tab,
    const float* __restrict__ nrgs,
    float* __restrict__ preds,
    float* __restrict__ reals)
{
    const int r = blockIdx.x * 256 + threadIdx.x;
    const int m = meta[r];
    float pred = 0.f, real = 0.f;
    if (m >= 0) {
        const int pos = m & 0xFFFF;
        const int wcv = (m >> 16) & 0xFF;
        const int mcv = (m >> 24) & 0xFF;
        pred = tab[pos * TABS + wcv] - tab[pos * TABS + mcv];
        real = nrgs[r];
    }
    preds[r] = pred;
    reals[r] = real;
}

extern "C" void kernel_launch(void* const* d_in, const int* in_sizes, int n_in,
                              void* d_out, int out_size, void* d_ws, size_t ws_size,
                              hipStream_t stream) {
    const float* all_input = (const float*)d_in[0];   // [512,128]
    const int*   seqs      = (const int*)  d_in[1];   // [1,512]
    const int*   muts      = (const int*)  d_in[2];   // [1,65536,512]
    const float* nrgs      = (const float*)d_in[3];   // [1,65536]
    const float* Wf        = (const float*)d_in[4];   // [128,128,9]
    const float* bf        = (const float*)d_in[5];
    // d_in[6]=Wa, d_in[7]=ba : dead (softmax over length-1 axis == 1)
    const float* W1 = (const float*)d_in[8];
    const float* b1 = (const float*)d_in[9];
    const float* W2 = (const float*)d_in[10];
    const float* b2 = (const float*)d_in[11];
    const float* W3 = (const float*)d_in[12];
    const float* b3 = (const float*)d_in[13];
    const float* W4 = (const float*)d_in[14];
    const float* b4 = (const float*)d_in[15];
    const float* Wd = (const float*)d_in[16];
    const float* bd = (const float*)d_in[17];

    float* tab  = (float*)d_ws;                        // 512*32*4 = 64 KiB
    int*   meta = (int*)((char*)d_ws + LSEQ * TABS * 4); // 65536*4 = 256 KiB
    float* preds = (float*)d_out;                      // [NMUT]
    float* reals = (float*)d_out + NMUT;               // [NMUT]

    fused_tab_scan_kernel<<<NB_TAB + NB_SCAN, 256, 0, stream>>>(
        all_input, seqs, muts,
        Wf, bf, W1, b1, W2, b2, W3, b3, W4, b4, Wd, bd,
        tab, meta);

    lookup_kernel<<<NMUT / 256, 256, 0, stream>>>(meta, tab, nrgs, preds, reals);
}